// Round 5
// baseline (535.460 us; speedup 1.0000x reference)
//
#include <hip/hip_runtime.h>
#include <hip/hip_fp16.h>

#define S 9216
#define F 256
#define W 96
#define HH 96
#define C 64
#define NH 8
#define KSPLIT 8
#define KV_PER_SPLIT (S / KSPLIT)   /* 1152 */
#define KTILE 64
#define NKT (KV_PER_SPLIT / KTILE)  /* 18 */

typedef _Float16 half8 __attribute__((ext_vector_type(8)));
typedef float floatx4 __attribute__((ext_vector_type(4)));

// Fragment-ordered layouts (1 KB contiguous per wave fragment-load):
//   Qf/Kf: [S/16 tiles][8 ch][64 lane][8 halves], element (s, f):
//          tile=s/16, ch=f/32, lane=(s%16)+16*((f%32)/8), j=f%8
//   Vf:    [S/32 kchunks][4 cs][64 lane][8 halves], element (c, k):
//          kchunk=k/32, cs=c/16, lane=(c%16)+16*((k%32)/8), j=k%8

// ---------------- row means (prev_Q rows: 2048, X rows: 256) ----------------
__global__ __launch_bounds__(256) void rowmean_kernel(
    const float* __restrict__ prevQ, const float* __restrict__ Xg,
    float* __restrict__ pqmean, float* __restrict__ xmean) {
  int row = blockIdx.x;
  const float4* src = (const float4*)((row < 2048) ? (prevQ + (size_t)row * S)
                                                   : (Xg + (size_t)(row - 2048) * S));
  float s = 0.f;
  #pragma unroll
  for (int j = 0; j < 9; j++) {           // 9 * 256 * 4 = 9216
    float4 v = src[j * 256 + threadIdx.x];
    s += v.x + v.y + v.z + v.w;
  }
  __shared__ float red[256];
  red[threadIdx.x] = s;
  __syncthreads();
  for (int off = 128; off > 0; off >>= 1) {
    if ((int)threadIdx.x < off) red[threadIdx.x] += red[threadIdx.x + off];
    __syncthreads();
  }
  if (threadIdx.x == 0) {
    float m = red[0] * (1.f / (float)S);
    if (row < 2048) pqmean[row] = m; else xmean[row - 2048] = m;
  }
}

// ---------------- per-feature coefficients ----------------
__global__ __launch_bounds__(256) void coef_kernel(
    const float* __restrict__ WQ_task, const float* __restrict__ BQ_task,
    const float* __restrict__ WK_task, const float* __restrict__ BK_task,
    const float* __restrict__ WQ_tm1, const float* __restrict__ WQ_x,
    const float* __restrict__ BQ, const float* __restrict__ WK_x,
    const float* __restrict__ BK, const float* __restrict__ pqmean,
    const float* __restrict__ xmean,
    float* __restrict__ qscale, float* __restrict__ c1, float* __restrict__ c0,
    float* __restrict__ kw, float* __restrict__ kb,
    float* __restrict__ qbar, float* __restrict__ kbar) {
  int f = threadIdx.x;  // F == 256 == blockDim.x
  float sumW = 0.f, sc0 = 0.f, qb = 0.f;
  for (int n = 0; n < NH; n++) {
    float wq = WQ_task[n * F + f];
    float qs = wq * WQ_tm1[n * F + f];
    qscale[f * NH + n] = qs;
    sumW += wq;
    sc0 += wq * BQ[n * F + f] + BQ_task[n * F + f];
    qb += qs * pqmean[n * F + f];
  }
  float c1v = WQ_x[f] * sumW;
  c1[f] = c1v; c0[f] = sc0;
  float kwv = WK_task[f] * WK_x[f];
  float kbv = WK_task[f] * BK[f] + BK_task[f];
  kw[f] = kwv; kb[f] = kbv;
  qbar[f] = qb + c1v * xmean[f] + sc0;
  kbar[f] = kwv * xmean[f] + kbv;
}

// ------- prep: centered Q'/K' (f16, fragment-ordered) + rowK -------
__global__ __launch_bounds__(256) void prep_kernel(
    const float* __restrict__ Xg, const float* __restrict__ prevQ,
    const float* __restrict__ qscale, const float* __restrict__ c1,
    const float* __restrict__ c0, const float* __restrict__ kw,
    const float* __restrict__ kb, const float* __restrict__ qbar,
    const float* __restrict__ kbar,
    _Float16* __restrict__ Qf, _Float16* __restrict__ Kf,
    float* __restrict__ rowK) {
  __shared__ float qt[32][33];
  __shared__ float kt[32][33];
  __shared__ float rk[8][32];
  int tx = threadIdx.x & 31, ty = threadIdx.x >> 5;
  int s0 = blockIdx.x * 32, f0 = blockIdx.y * 32;
  int s = s0 + tx;
  float rkacc = 0.f;
  for (int fi = ty; fi < 32; fi += 8) {
    int f = f0 + fi;
    float x = Xg[(size_t)f * S + s];
    float q = c1[f] * x + c0[f];
    #pragma unroll
    for (int n = 0; n < NH; n++)
      q += qscale[f * NH + n] * prevQ[((size_t)n * F + f) * S + s];
    q -= qbar[f];
    float k = kw[f] * x + kb[f] - kbar[f];
    qt[fi][tx] = q;
    kt[fi][tx] = k;
    rkacc += qbar[f] * k;
  }
  rk[ty][tx] = rkacc;
  __syncthreads();
  // fragment-ordered write: threads 0..127 -> Q, 128..255 -> K
  {
    int t = threadIdx.x;
    int isK = t >> 7;
    int tt = t & 127;
    int s_sub = tt >> 2, lw = tt & 3;   // lw = f-group of 8
    half8 h;
    #pragma unroll
    for (int jj = 0; jj < 8; jj++) {
      float v = isK ? kt[lw * 8 + jj][s_sub] : qt[lw * 8 + jj][s_sub];
      h[jj] = (_Float16)v;
    }
    size_t fi = (size_t)((s0 + s_sub) >> 4) * 8 + (f0 >> 5);
    int lane = (s_sub & 15) + 16 * lw;
    half8* dst = (half8*)(isK ? Kf : Qf);
    dst[fi * 64 + lane] = h;
  }
  if (ty == 0) {
    float t = 0.f;
    #pragma unroll
    for (int i = 0; i < 8; i++) t += rk[i][tx];
    atomicAdd(&rowK[s], t);
  }
}

// ------- 3x3 SAME conv F->C + affine -> Vf (f16, fragment-ordered) -------
__global__ __launch_bounds__(256) void conv_kernel(
    const float* __restrict__ Xg, const float* __restrict__ Wc,
    const float* __restrict__ bias, const float* __restrict__ WV_task,
    const float* __restrict__ BV_task, _Float16* __restrict__ Vf) {
  __shared__ float wlds[4 * 2304];
  int c0 = blockIdx.y * 4;
  for (int i = threadIdx.x; i < 4 * 2304; i += 256)
    wlds[i] = Wc[(size_t)c0 * 2304 + i];
  __syncthreads();
  int p = blockIdx.x * 256 + threadIdx.x;
  int w = p / HH, h = p % HH;
  float acc0 = 0.f, acc1 = 0.f, acc2 = 0.f, acc3 = 0.f;
  for (int f = 0; f < F; f++) {
    const float* xp = Xg + (size_t)f * S;
    float xv[9];
    #pragma unroll
    for (int ky = 0; ky < 3; ky++) {
      int ww = w + ky - 1;
      #pragma unroll
      for (int kx = 0; kx < 3; kx++) {
        int hh = h + kx - 1;
        xv[ky * 3 + kx] = (ww >= 0 && ww < W && hh >= 0 && hh < HH)
                              ? xp[ww * HH + hh] : 0.f;
      }
    }
    const float* wl = wlds + f * 9;
    #pragma unroll
    for (int t = 0; t < 9; t++) {
      float x = xv[t];
      acc0 += x * wl[t];
      acc1 += x * wl[2304 + t];
      acc2 += x * wl[2 * 2304 + t];
      acc3 += x * wl[3 * 2304 + t];
    }
  }
  float accs[4] = {acc0, acc1, acc2, acc3};
  int k = p;
  #pragma unroll
  for (int cc = 0; cc < 4; cc++) {
    int c = c0 + cc;
    float v = WV_task[c] * (accs[cc] + bias[c]) + BV_task[c];
    size_t idx = (((size_t)(k >> 5) * 4 + (c >> 4)) * 64 +
                  ((c & 15) + 16 * ((k & 31) >> 3))) * 8 + (k & 7);
    Vf[idx] = (_Float16)v;
  }
}

// ---- flash attention: 4 waves x 32 q-rows, K/V staged in LDS, split-K ----
__global__ __launch_bounds__(256, 2) void flash_kernel(
    const _Float16* __restrict__ Qf, const _Float16* __restrict__ Kf,
    const _Float16* __restrict__ Vf, const float* __restrict__ rowK,
    float* __restrict__ out_part, float* __restrict__ m_part,
    float* __restrict__ l_part) {
  int qt = blockIdx.x, sp = blockIdx.y;
  int wave = threadIdx.x >> 6, lane = threadIdx.x & 63;
  int lr = lane & 15, lhi = lane >> 4;
  __shared__ __align__(16) _Float16 kvbuf[2560 * 8];  // 32 KB K + 8 KB V
  __shared__ __align__(16) _Float16 plds[4][16][72];
  half8* ldsv = (half8*)kvbuf;

  // Q A-fragments: 2 q-subtiles (32 rows) per wave, loop-invariant
  half8 qfrag[2][8];
  {
    const half8* qb = (const half8*)Qf;
    #pragma unroll
    for (int qs = 0; qs < 2; qs++) {
      size_t t16 = (size_t)(qt * 8 + wave * 2 + qs) * 8;
      #pragma unroll
      for (int ch = 0; ch < 8; ch++) qfrag[qs][ch] = qb[(t16 + ch) * 64 + lane];
    }
  }

  floatx4 oacc[2][4] = {};
  float m_run[2][4], l_run[2][4];
  #pragma unroll
  for (int qs = 0; qs < 2; qs++)
    #pragma unroll
    for (int j = 0; j < 4; j++) { m_run[qs][j] = -1e30f; l_run[qs][j] = 0.f; }

  for (int kt = 0; kt < NKT; kt++) {
    int k0 = sp * KV_PER_SPLIT + kt * KTILE;
    const half8* ksrc = (const half8*)Kf + (size_t)(k0 >> 4) * 512;
    const half8* vsrc = (const half8*)Vf + (size_t)(k0 >> 5) * 256;
    __syncthreads();                       // prev tile fully consumed
    #pragma unroll
    for (int j = 0; j < 10; j++) {         // 2560 half8 = 40 KB staged
      int idx = j * 256 + (int)threadIdx.x;
      const half8* src = (idx < 2048) ? (ksrc + idx) : (vsrc + (idx - 2048));
      ldsv[idx] = *src;
    }
    __syncthreads();                       // staging visible

    float rk4[4];
    #pragma unroll
    for (int ks = 0; ks < 4; ks++) rk4[ks] = rowK[k0 + ks * 16 + lr];

    // ---- QK^T: 64 MFMA from LDS K-frags (each read once, used 2x) ----
    floatx4 sacc[2][4] = {};
    #pragma unroll
    for (int ch = 0; ch < 8; ch++) {
      #pragma unroll
      for (int ks = 0; ks < 4; ks++) {
        half8 kf = ldsv[(ks * 8 + ch) * 64 + lane];
        sacc[0][ks] = __builtin_amdgcn_mfma_f32_16x16x32_f16(qfrag[0][ch], kf,
                                                             sacc[0][ks], 0, 0, 0);
        sacc[1][ks] = __builtin_amdgcn_mfma_f32_16x16x32_f16(qfrag[1][ch], kf,
                                                             sacc[1][ks], 0, 0, 0);
      }
    }

    // ---- per-subtile softmax + PV ----
    #pragma unroll
    for (int qs = 0; qs < 2; qs++) {
      float tmax[4];
      #pragma unroll
      for (int j = 0; j < 4; j++) tmax[j] = -1e30f;
      #pragma unroll
      for (int ks = 0; ks < 4; ks++) {
        #pragma unroll
        for (int j = 0; j < 4; j++) {
          sacc[qs][ks][j] += rk4[ks];
          tmax[j] = fmaxf(tmax[j], sacc[qs][ks][j]);
        }
      }
      #pragma unroll
      for (int off = 1; off < 16; off <<= 1)
        #pragma unroll
        for (int j = 0; j < 4; j++)
          tmax[j] = fmaxf(tmax[j], __shfl_xor(tmax[j], off, 64));

      float ef[4], rsum[4];
      #pragma unroll
      for (int j = 0; j < 4; j++) {
        float mn = fmaxf(m_run[qs][j], tmax[j]);
        ef[j] = __expf(m_run[qs][j] - mn);
        m_run[qs][j] = mn;
        rsum[j] = 0.f;
      }
      #pragma unroll
      for (int ks = 0; ks < 4; ks++) {
        #pragma unroll
        for (int j = 0; j < 4; j++) {
          float p = __expf(sacc[qs][ks][j] - m_run[qs][j]);
          rsum[j] += p;
          plds[wave][lhi * 4 + j][ks * 16 + lr] = (_Float16)p;
        }
      }
      #pragma unroll
      for (int off = 1; off < 16; off <<= 1)
        #pragma unroll
        for (int j = 0; j < 4; j++) rsum[j] += __shfl_xor(rsum[j], off, 64);
      #pragma unroll
      for (int j = 0; j < 4; j++)
        l_run[qs][j] = l_run[qs][j] * ef[j] + rsum[j];
      #pragma unroll
      for (int cs = 0; cs < 4; cs++)
        #pragma unroll
        for (int j = 0; j < 4; j++) oacc[qs][cs][j] *= ef[j];

      #pragma unroll
      for (int kc = 0; kc < 2; kc++) {
        half8 pfrag = *(const half8*)(&plds[wave][lr][kc * 32 + lhi * 8]);
        #pragma unroll
        for (int cs = 0; cs < 4; cs++) {
          half8 vfrag = ldsv[2048 + (kc * 4 + cs) * 64 + lane];
          oacc[qs][cs] = __builtin_amdgcn_mfma_f32_16x16x32_f16(pfrag, vfrag,
                                                                oacc[qs][cs], 0, 0, 0);
        }
      }
    }
  }

  #pragma unroll
  for (int qs = 0; qs < 2; qs++) {
    size_t base = (size_t)sp * S + qt * 128 + wave * 32 + qs * 16;
    #pragma unroll
    for (int cs = 0; cs < 4; cs++)
      #pragma unroll
      for (int j = 0; j < 4; j++)
        out_part[(base + lhi * 4 + j) * C + cs * 16 + lr] = oacc[qs][cs][j];
    if (lr == 0) {
      #pragma unroll
      for (int j = 0; j < 4; j++) {
        m_part[base + lhi * 4 + j] = m_run[qs][j];
        l_part[base + lhi * 4 + j] = l_run[qs][j];
      }
    }
  }
}

// ---------------- combine split-K partials ----------------
__global__ __launch_bounds__(256) void combine_kernel(
    const float* __restrict__ out_part, const float* __restrict__ m_part,
    const float* __restrict__ l_part, float* __restrict__ out) {
  int q = blockIdx.x * 4 + (threadIdx.x >> 6);
  int c = threadIdx.x & 63;
  float m = -1e30f;
  #pragma unroll
  for (int i = 0; i < KSPLIT; i++) m = fmaxf(m, m_part[(size_t)i * S + q]);
  float l = 0.f, acc = 0.f;
  #pragma unroll
  for (int i = 0; i < KSPLIT; i++) {
    float wgt = __expf(m_part[(size_t)i * S + q] - m);
    l += wgt * l_part[(size_t)i * S + q];
    acc += wgt * out_part[((size_t)i * S + q) * C + c];
  }
  out[(size_t)c * S + q] = acc / l;
}

extern "C" void kernel_launch(void* const* d_in, const int* in_sizes, int n_in,
                              void* d_out, int out_size, void* d_ws,
                              size_t ws_size, hipStream_t stream) {
  const float* Xg      = (const float*)d_in[0];
  const float* WQ_task = (const float*)d_in[1];
  const float* BQ_task = (const float*)d_in[2];
  const float* WK_task = (const float*)d_in[3];
  const float* BK_task = (const float*)d_in[4];
  const float* WV_task = (const float*)d_in[5];
  const float* BV_task = (const float*)d_in[6];
  const float* WQ_tm1  = (const float*)d_in[7];
  const float* WQ_x    = (const float*)d_in[8];
  const float* BQ      = (const float*)d_in[9];
  const float* WK_x    = (const float*)d_in[10];
  const float* BK      = (const float*)d_in[11];
  const float* prevQ   = (const float*)d_in[12];
  const float* Wc      = (const float*)d_in[13];
  const float* bias    = (const float*)d_in[14];
  float* out = (float*)d_out;

  char* ws = (char*)d_ws;
  size_t off = 0;
  auto alloc = [&](size_t bytes) {
    void* p = ws + off;
    off += (bytes + 255) & ~(size_t)255;
    return p;
  };
  _Float16* Qf   = (_Float16*)alloc((size_t)S * F * 2);
  _Float16* Kf   = (_Float16*)alloc((size_t)S * F * 2);
  _Float16* Vf   = (_Float16*)alloc((size_t)C * S * 2);
  float* rowK    = (float*)alloc((size_t)S * 4);
  float* pqmean  = (float*)alloc(2048 * 4);
  float* xmean   = (float*)alloc(256 * 4);
  float* qscale  = (float*)alloc(256 * 8 * 4);
  float* c1      = (float*)alloc(256 * 4);
  float* c0      = (float*)alloc(256 * 4);
  float* kw      = (float*)alloc(256 * 4);
  float* kb      = (float*)alloc(256 * 4);
  float* qbar    = (float*)alloc(256 * 4);
  float* kbar    = (float*)alloc(256 * 4);
  float* out_part = (float*)alloc((size_t)KSPLIT * S * C * 4);
  float* m_part   = (float*)alloc((size_t)KSPLIT * S * 4);
  float* l_part   = (float*)alloc((size_t)KSPLIT * S * 4);

  hipMemsetAsync(rowK, 0, (size_t)S * 4, stream);

  rowmean_kernel<<<2304, 256, 0, stream>>>(prevQ, Xg, pqmean, xmean);
  coef_kernel<<<1, 256, 0, stream>>>(WQ_task, BQ_task, WK_task, BK_task,
                                     WQ_tm1, WQ_x, BQ, WK_x, BK, pqmean, xmean,
                                     qscale, c1, c0, kw, kb, qbar, kbar);
  prep_kernel<<<dim3(S / 32, F / 32), 256, 0, stream>>>(
      Xg, prevQ, qscale, c1, c0, kw, kb, qbar, kbar, Qf, Kf, rowK);
  conv_kernel<<<dim3(S / 256, C / 4), 256, 0, stream>>>(Xg, Wc, bias, WV_task,
                                                        BV_task, Vf);
  flash_kernel<<<dim3(S / 128, KSPLIT), 256, 0, stream>>>(
      Qf, Kf, Vf, rowK, out_part, m_part, l_part);
  combine_kernel<<<S / 4, 256, 0, stream>>>(out_part, m_part, l_part, out);
}

// Round 6
// 472.865 us; speedup vs baseline: 1.1324x; 1.1324x over previous
//
#include <hip/hip_runtime.h>
#include <hip/hip_fp16.h>

#define S 9216
#define F 256
#define W 96
#define HH 96
#define C 64
#define NH 8
#define KSPLIT 16
#define KV_PER_SPLIT (S / KSPLIT)   /* 576 */
#define KTILE 32
#define NKT (KV_PER_SPLIT / KTILE)  /* 18 */
#define TILE_H8 1280                /* half8 per tile: K 1024 (16KB) + V 256 (4KB) */

typedef _Float16 half8 __attribute__((ext_vector_type(8)));
typedef float floatx4 __attribute__((ext_vector_type(4)));

// Fragment-ordered layouts (1 KB contiguous per wave fragment-load):
//   Qf/Kf: [S/16 tiles][8 ch][64 lane][8 halves], element (s, f):
//          tile=s/16, ch=f/32, lane=(s%16)+16*((f%32)/8), j=f%8
//   Vf:    [S/32 kchunks][4 cs][64 lane][8 halves], element (c, k):
//          kchunk=k/32, cs=c/16, lane=(c%16)+16*((k%32)/8), j=k%8

// ---------------- row means (prev_Q rows: 2048, X rows: 256) ----------------
__global__ __launch_bounds__(256) void rowmean_kernel(
    const float* __restrict__ prevQ, const float* __restrict__ Xg,
    float* __restrict__ pqmean, float* __restrict__ xmean) {
  int row = blockIdx.x;
  const float4* src = (const float4*)((row < 2048) ? (prevQ + (size_t)row * S)
                                                   : (Xg + (size_t)(row - 2048) * S));
  float s = 0.f;
  #pragma unroll
  for (int j = 0; j < 9; j++) {           // 9 * 256 * 4 = 9216
    float4 v = src[j * 256 + threadIdx.x];
    s += v.x + v.y + v.z + v.w;
  }
  __shared__ float red[256];
  red[threadIdx.x] = s;
  __syncthreads();
  for (int off = 128; off > 0; off >>= 1) {
    if ((int)threadIdx.x < off) red[threadIdx.x] += red[threadIdx.x + off];
    __syncthreads();
  }
  if (threadIdx.x == 0) {
    float m = red[0] * (1.f / (float)S);
    if (row < 2048) pqmean[row] = m; else xmean[row - 2048] = m;
  }
}

// ---------------- per-feature coefficients ----------------
__global__ __launch_bounds__(256) void coef_kernel(
    const float* __restrict__ WQ_task, const float* __restrict__ BQ_task,
    const float* __restrict__ WK_task, const float* __restrict__ BK_task,
    const float* __restrict__ WQ_tm1, const float* __restrict__ WQ_x,
    const float* __restrict__ BQ, const float* __restrict__ WK_x,
    const float* __restrict__ BK, const float* __restrict__ pqmean,
    const float* __restrict__ xmean,
    float* __restrict__ qscale, float* __restrict__ c1, float* __restrict__ c0,
    float* __restrict__ kw, float* __restrict__ kb,
    float* __restrict__ qbar, float* __restrict__ kbar) {
  int f = threadIdx.x;  // F == 256 == blockDim.x
  float sumW = 0.f, sc0 = 0.f, qb = 0.f;
  for (int n = 0; n < NH; n++) {
    float wq = WQ_task[n * F + f];
    float qs = wq * WQ_tm1[n * F + f];
    qscale[f * NH + n] = qs;
    sumW += wq;
    sc0 += wq * BQ[n * F + f] + BQ_task[n * F + f];
    qb += qs * pqmean[n * F + f];
  }
  float c1v = WQ_x[f] * sumW;
  c1[f] = c1v; c0[f] = sc0;
  float kwv = WK_task[f] * WK_x[f];
  float kbv = WK_task[f] * BK[f] + BK_task[f];
  kw[f] = kwv; kb[f] = kbv;
  qbar[f] = qb + c1v * xmean[f] + sc0;
  kbar[f] = kwv * xmean[f] + kbv;
}

// ------- prep: centered Q'/K' (f16, fragment-ordered) + rowK -------
__global__ __launch_bounds__(256) void prep_kernel(
    const float* __restrict__ Xg, const float* __restrict__ prevQ,
    const float* __restrict__ qscale, const float* __restrict__ c1,
    const float* __restrict__ c0, const float* __restrict__ kw,
    const float* __restrict__ kb, const float* __restrict__ qbar,
    const float* __restrict__ kbar,
    _Float16* __restrict__ Qf, _Float16* __restrict__ Kf,
    float* __restrict__ rowK) {
  __shared__ float qt[32][33];
  __shared__ float kt[32][33];
  __shared__ float rk[8][32];
  int tx = threadIdx.x & 31, ty = threadIdx.x >> 5;
  int s0 = blockIdx.x * 32, f0 = blockIdx.y * 32;
  int s = s0 + tx;
  float rkacc = 0.f;
  for (int fi = ty; fi < 32; fi += 8) {
    int f = f0 + fi;
    float x = Xg[(size_t)f * S + s];
    float q = c1[f] * x + c0[f];
    #pragma unroll
    for (int n = 0; n < NH; n++)
      q += qscale[f * NH + n] * prevQ[((size_t)n * F + f) * S + s];
    q -= qbar[f];
    float k = kw[f] * x + kb[f] - kbar[f];
    qt[fi][tx] = q;
    kt[fi][tx] = k;
    rkacc += qbar[f] * k;
  }
  rk[ty][tx] = rkacc;
  __syncthreads();
  // fragment-ordered write: threads 0..127 -> Q, 128..255 -> K
  {
    int t = threadIdx.x;
    int isK = t >> 7;
    int tt = t & 127;
    int s_sub = tt >> 2, lw = tt & 3;   // lw = f-group of 8
    half8 h;
    #pragma unroll
    for (int jj = 0; jj < 8; jj++) {
      float v = isK ? kt[lw * 8 + jj][s_sub] : qt[lw * 8 + jj][s_sub];
      h[jj] = (_Float16)v;
    }
    size_t fi = (size_t)((s0 + s_sub) >> 4) * 8 + (f0 >> 5);
    int lane = (s_sub & 15) + 16 * lw;
    half8* dst = (half8*)(isK ? Kf : Qf);
    dst[fi * 64 + lane] = h;
  }
  if (ty == 0) {
    float t = 0.f;
    #pragma unroll
    for (int i = 0; i < 8; i++) t += rk[i][tx];
    atomicAdd(&rowK[s], t);
  }
}

// ------- 3x3 SAME conv F->C + affine -> Vf (f16, fragment-ordered) -------
__global__ __launch_bounds__(256) void conv_kernel(
    const float* __restrict__ Xg, const float* __restrict__ Wc,
    const float* __restrict__ bias, const float* __restrict__ WV_task,
    const float* __restrict__ BV_task, _Float16* __restrict__ Vf) {
  __shared__ float wlds[4 * 2304];
  int c0 = blockIdx.y * 4;
  for (int i = threadIdx.x; i < 4 * 2304; i += 256)
    wlds[i] = Wc[(size_t)c0 * 2304 + i];
  __syncthreads();
  int p = blockIdx.x * 256 + threadIdx.x;
  int w = p / HH, h = p % HH;
  float acc0 = 0.f, acc1 = 0.f, acc2 = 0.f, acc3 = 0.f;
  for (int f = 0; f < F; f++) {
    const float* xp = Xg + (size_t)f * S;
    float xv[9];
    #pragma unroll
    for (int ky = 0; ky < 3; ky++) {
      int ww = w + ky - 1;
      #pragma unroll
      for (int kx = 0; kx < 3; kx++) {
        int hh = h + kx - 1;
        xv[ky * 3 + kx] = (ww >= 0 && ww < W && hh >= 0 && hh < HH)
                              ? xp[ww * HH + hh] : 0.f;
      }
    }
    const float* wl = wlds + f * 9;
    #pragma unroll
    for (int t = 0; t < 9; t++) {
      float x = xv[t];
      acc0 += x * wl[t];
      acc1 += x * wl[2304 + t];
      acc2 += x * wl[2 * 2304 + t];
      acc3 += x * wl[3 * 2304 + t];
    }
  }
  float accs[4] = {acc0, acc1, acc2, acc3};
  int k = p;
  #pragma unroll
  for (int cc = 0; cc < 4; cc++) {
    int c = c0 + cc;
    float v = WV_task[c] * (accs[cc] + bias[c]) + BV_task[c];
    size_t idx = (((size_t)(k >> 5) * 4 + (c >> 4)) * 64 +
                  ((c & 15) + 16 * ((k & 31) >> 3))) * 8 + (k & 7);
    Vf[idx] = (_Float16)v;
  }
}

// ---- flash: 4 waves x 32 q-rows, dbuf LDS K/V, 1 barrier/tile, split-K ----
__global__ __launch_bounds__(256, 3) void flash_kernel(
    const _Float16* __restrict__ Qf, const _Float16* __restrict__ Kf,
    const _Float16* __restrict__ Vf, const float* __restrict__ rowK,
    _Float16* __restrict__ out_part, float* __restrict__ m_part,
    float* __restrict__ l_part) {
  int qt = blockIdx.x, sp = blockIdx.y;
  int wave = threadIdx.x >> 6, lane = threadIdx.x & 63;
  int tid = threadIdx.x;
  int lr = lane & 15, lhi = lane >> 4;
  __shared__ __align__(16) half8 kv[2][TILE_H8];   // 2 x 20 KB
  __shared__ __align__(16) _Float16 plds[4][16][40];

  // Q A-fragments: 2 q-subtiles (32 rows) per wave, loop-invariant
  half8 qfrag[2][8];
  #pragma unroll
  for (int qs = 0; qs < 2; qs++) {
    size_t t16 = (size_t)(qt * 8 + wave * 2 + qs) * 8;
    #pragma unroll
    for (int ch = 0; ch < 8; ch++)
      qfrag[qs][ch] = ((const half8*)Qf)[(t16 + ch) * 64 + lane];
  }

  floatx4 oacc[2][4] = {};
  float m_run[2][4], l_run[2][4];
  #pragma unroll
  for (int qs = 0; qs < 2; qs++)
    #pragma unroll
    for (int j = 0; j < 4; j++) { m_run[qs][j] = -1e30f; l_run[qs][j] = 0.f; }

  // prologue: stage tile 0 into kv[0]
  {
    int k0 = sp * KV_PER_SPLIT;
    const half8* ks = (const half8*)Kf + (size_t)(k0 >> 4) * 512;
    const half8* vs = (const half8*)Vf + (size_t)(k0 >> 5) * 256;
    #pragma unroll
    for (int u = 0; u < 5; u++) {
      int idx = u * 256 + tid;
      kv[0][idx] = (idx < 1024) ? ks[idx] : vs[idx - 1024];
    }
  }

  int cur = 0;
  for (int kt = 0; kt < NKT; kt++) {
    int k0 = sp * KV_PER_SPLIT + kt * KTILE;
    // ---- issue next tile's global loads (consumed by ds_write after compute)
    half8 stg[5];
    if (kt + 1 < NKT) {
      const half8* ks = (const half8*)Kf + (size_t)((k0 + KTILE) >> 4) * 512;
      const half8* vs = (const half8*)Vf + (size_t)((k0 + KTILE) >> 5) * 256;
      #pragma unroll
      for (int u = 0; u < 5; u++) {
        int idx = u * 256 + tid;
        stg[u] = (idx < 1024) ? ks[idx] : vs[idx - 1024];
      }
    }
    __builtin_amdgcn_sched_barrier(0);   // don't sink the loads into compute
    __syncthreads();                     // staging of kv[cur] visible

    float rk4[2];
    #pragma unroll
    for (int ks = 0; ks < 2; ks++) rk4[ks] = rowK[k0 + ks * 16 + lr];

    // ---- QK^T: K-frag read once, used for both q-subtiles ----
    floatx4 sacc[2][2] = {};
    #pragma unroll
    for (int ch = 0; ch < 8; ch++) {
      #pragma unroll
      for (int ks = 0; ks < 2; ks++) {
        half8 kf = kv[cur][(ks * 8 + ch) * 64 + lane];
        sacc[0][ks] = __builtin_amdgcn_mfma_f32_16x16x32_f16(qfrag[0][ch], kf,
                                                             sacc[0][ks], 0, 0, 0);
        sacc[1][ks] = __builtin_amdgcn_mfma_f32_16x16x32_f16(qfrag[1][ch], kf,
                                                             sacc[1][ks], 0, 0, 0);
      }
    }

    // ---- per-subtile softmax + PV ----
    #pragma unroll
    for (int qs = 0; qs < 2; qs++) {
      float tmax[4];
      #pragma unroll
      for (int j = 0; j < 4; j++) tmax[j] = -1e30f;
      #pragma unroll
      for (int ks = 0; ks < 2; ks++) {
        #pragma unroll
        for (int j = 0; j < 4; j++) {
          sacc[qs][ks][j] += rk4[ks];
          tmax[j] = fmaxf(tmax[j], sacc[qs][ks][j]);
        }
      }
      #pragma unroll
      for (int off = 1; off < 16; off <<= 1)
        #pragma unroll
        for (int j = 0; j < 4; j++)
          tmax[j] = fmaxf(tmax[j], __shfl_xor(tmax[j], off, 64));

      float ef[4], rsum[4];
      #pragma unroll
      for (int j = 0; j < 4; j++) {
        float mn = fmaxf(m_run[qs][j], tmax[j]);
        ef[j] = __expf(m_run[qs][j] - mn);
        m_run[qs][j] = mn;
        rsum[j] = 0.f;
      }
      #pragma unroll
      for (int ks = 0; ks < 2; ks++) {
        #pragma unroll
        for (int j = 0; j < 4; j++) {
          float p = __expf(sacc[qs][ks][j] - m_run[qs][j]);
          rsum[j] += p;
          plds[wave][lhi * 4 + j][ks * 16 + lr] = (_Float16)p;
        }
      }
      #pragma unroll
      for (int off = 1; off < 16; off <<= 1)
        #pragma unroll
        for (int j = 0; j < 4; j++) rsum[j] += __shfl_xor(rsum[j], off, 64);
      #pragma unroll
      for (int j = 0; j < 4; j++)
        l_run[qs][j] = l_run[qs][j] * ef[j] + rsum[j];
      #pragma unroll
      for (int cs = 0; cs < 4; cs++)
        #pragma unroll
        for (int j = 0; j < 4; j++) oacc[qs][cs][j] *= ef[j];

      half8 pfrag = *(const half8*)(&plds[wave][lr][lhi * 8]);
      #pragma unroll
      for (int cs = 0; cs < 4; cs++) {
        half8 vfrag = kv[cur][1024 + cs * 64 + lane];
        oacc[qs][cs] = __builtin_amdgcn_mfma_f32_16x16x32_f16(pfrag, vfrag,
                                                              oacc[qs][cs], 0, 0, 0);
      }
    }

    // ---- write staged tile into other buffer (vmcnt wait lands here) ----
    if (kt + 1 < NKT) {
      #pragma unroll
      for (int u = 0; u < 5; u++) kv[cur ^ 1][u * 256 + tid] = stg[u];
    }
    cur ^= 1;
  }

  #pragma unroll
  for (int qs = 0; qs < 2; qs++) {
    size_t base = (size_t)sp * S + qt * 128 + wave * 32 + qs * 16;
    #pragma unroll
    for (int cs = 0; cs < 4; cs++)
      #pragma unroll
      for (int j = 0; j < 4; j++)
        out_part[(base + lhi * 4 + j) * C + cs * 16 + lr] =
            (_Float16)oacc[qs][cs][j];
    if (lr == 0) {
      #pragma unroll
      for (int j = 0; j < 4; j++) {
        m_part[base + lhi * 4 + j] = m_run[qs][j];
        l_part[base + lhi * 4 + j] = l_run[qs][j];
      }
    }
  }
}

// ---------------- combine split-K partials ----------------
__global__ __launch_bounds__(256) void combine_kernel(
    const _Float16* __restrict__ out_part, const float* __restrict__ m_part,
    const float* __restrict__ l_part, float* __restrict__ out) {
  int q = blockIdx.x * 4 + (threadIdx.x >> 6);
  int c = threadIdx.x & 63;
  float m = -1e30f;
  #pragma unroll
  for (int i = 0; i < KSPLIT; i++) m = fmaxf(m, m_part[(size_t)i * S + q]);
  float l = 0.f, acc = 0.f;
  #pragma unroll
  for (int i = 0; i < KSPLIT; i++) {
    float wgt = __expf(m_part[(size_t)i * S + q] - m);
    l += wgt * l_part[(size_t)i * S + q];
    acc += wgt * (float)out_part[((size_t)i * S + q) * C + c];
  }
  out[(size_t)c * S + q] = acc / l;
}

extern "C" void kernel_launch(void* const* d_in, const int* in_sizes, int n_in,
                              void* d_out, int out_size, void* d_ws,
                              size_t ws_size, hipStream_t stream) {
  const float* Xg      = (const float*)d_in[0];
  const float* WQ_task = (const float*)d_in[1];
  const float* BQ_task = (const float*)d_in[2];
  const float* WK_task = (const float*)d_in[3];
  const float* BK_task = (const float*)d_in[4];
  const float* WV_task = (const float*)d_in[5];
  const float* BV_task = (const float*)d_in[6];
  const float* WQ_tm1  = (const float*)d_in[7];
  const float* WQ_x    = (const float*)d_in[8];
  const float* BQ      = (const float*)d_in[9];
  const float* WK_x    = (const float*)d_in[10];
  const float* BK      = (const float*)d_in[11];
  const float* prevQ   = (const float*)d_in[12];
  const float* Wc      = (const float*)d_in[13];
  const float* bias    = (const float*)d_in[14];
  float* out = (float*)d_out;

  char* ws = (char*)d_ws;
  size_t off = 0;
  auto alloc = [&](size_t bytes) {
    void* p = ws + off;
    off += (bytes + 255) & ~(size_t)255;
    return p;
  };
  _Float16* Qf   = (_Float16*)alloc((size_t)S * F * 2);
  _Float16* Kf   = (_Float16*)alloc((size_t)S * F * 2);
  _Float16* Vf   = (_Float16*)alloc((size_t)C * S * 2);
  float* rowK    = (float*)alloc((size_t)S * 4);
  float* pqmean  = (float*)alloc(2048 * 4);
  float* xmean   = (float*)alloc(256 * 4);
  float* qscale  = (float*)alloc(256 * 8 * 4);
  float* c1      = (float*)alloc(256 * 4);
  float* c0      = (float*)alloc(256 * 4);
  float* kw      = (float*)alloc(256 * 4);
  float* kb      = (float*)alloc(256 * 4);
  float* qbar    = (float*)alloc(256 * 4);
  float* kbar    = (float*)alloc(256 * 4);
  _Float16* out_part = (_Float16*)alloc((size_t)KSPLIT * S * C * 2);
  float* m_part   = (float*)alloc((size_t)KSPLIT * S * 4);
  float* l_part   = (float*)alloc((size_t)KSPLIT * S * 4);

  hipMemsetAsync(rowK, 0, (size_t)S * 4, stream);

  rowmean_kernel<<<2304, 256, 0, stream>>>(prevQ, Xg, pqmean, xmean);
  coef_kernel<<<1, 256, 0, stream>>>(WQ_task, BQ_task, WK_task, BK_task,
                                     WQ_tm1, WQ_x, BQ, WK_x, BK, pqmean, xmean,
                                     qscale, c1, c0, kw, kb, qbar, kbar);
  prep_kernel<<<dim3(S / 32, F / 32), 256, 0, stream>>>(
      Xg, prevQ, qscale, c1, c0, kw, kb, qbar, kbar, Qf, Kf, rowK);
  conv_kernel<<<dim3(S / 256, C / 4), 256, 0, stream>>>(Xg, Wc, bias, WV_task,
                                                        BV_task, Vf);
  flash_kernel<<<dim3(S / 128, KSPLIT), 256, 0, stream>>>(
      Qf, Kf, Vf, rowK, out_part, m_part, l_part);
  combine_kernel<<<S / 4, 256, 0, stream>>>(out_part, m_part, l_part, out);
}